// Round 1
// baseline (920.267 us; speedup 1.0000x reference)
//
#include <hip/hip_runtime.h>
#include <hip/hip_bf16.h>

#define T_TOK 4096
#define H_DIM 2048
#define F_DIM 1280
#define NE 12
#define LDST 40  // LDS row stride in bf16 elems (32 + 8 pad)

typedef float f32x4 __attribute__((ext_vector_type(4)));
typedef short bf16x8 __attribute__((ext_vector_type(8)));

__device__ __forceinline__ unsigned short f2bf(float f) {
    unsigned int u = __float_as_uint(f);
    u += 0x7FFFu + ((u >> 16) & 1u);   // RNE
    return (unsigned short)(u >> 16);
}

// ---------------- gating: fp32 logits, top-2, normalized weights ----------------
__global__ __launch_bounds__(256) void gate_kernel(
    const float* __restrict__ x, const float* __restrict__ gw,
    int* __restrict__ counts, int* __restrict__ top_e, float* __restrict__ top_w)
{
    int gid = blockIdx.x * blockDim.x + threadIdx.x;
    int tok = gid >> 6;
    int lane = threadIdx.x & 63;
    if (tok >= T_TOK) return;
    const float* xr = x + (size_t)tok * H_DIM;
    float4 xs[8];
#pragma unroll
    for (int c = 0; c < 8; ++c) xs[c] = *(const float4*)(xr + c * 256 + lane * 4);
    float acc[NE];
#pragma unroll
    for (int e = 0; e < NE; ++e) {
        const float* gr = gw + (size_t)e * H_DIM;
        float s = 0.f;
#pragma unroll
        for (int c = 0; c < 8; ++c) {
            float4 g = *(const float4*)(gr + c * 256 + lane * 4);
            s += xs[c].x * g.x + xs[c].y * g.y + xs[c].z * g.z + xs[c].w * g.w;
        }
        acc[e] = s;
    }
#pragma unroll
    for (int e = 0; e < NE; ++e) {
#pragma unroll
        for (int off = 32; off > 0; off >>= 1)
            acc[e] += __shfl_xor(acc[e], off, 64);
    }
    if (lane == 0) {
        int b0 = 0;
#pragma unroll
        for (int e = 1; e < NE; ++e) if (acc[e] > acc[b0]) b0 = e;   // lowest idx on tie
        int b1 = (b0 == 0) ? 1 : 0;
#pragma unroll
        for (int e = 0; e < NE; ++e) if (e != b0 && acc[e] > acc[b1]) b1 = e;
        float t = __expf(acc[b1] - acc[b0]);   // <= 1
        float w0 = 1.f / (1.f + t);
        top_e[tok * 2] = b0; top_e[tok * 2 + 1] = b1;
        top_w[tok * 2] = w0; top_w[tok * 2 + 1] = 1.f - w0;
        atomicAdd(&counts[b0], 1);
        atomicAdd(&counts[b1], 1);
    }
}

__global__ void scan_kernel(const int* __restrict__ counts, int* __restrict__ offsets,
                            int* __restrict__ cursors)
{
    if (threadIdx.x == 0 && blockIdx.x == 0) {
        int s = 0;
        for (int e = 0; e < NE; ++e) { offsets[e] = s; s += counts[e]; cursors[e] = 0; }
        offsets[NE] = s;
    }
}

__global__ __launch_bounds__(256) void scatter_kernel(
    const int* __restrict__ top_e, const float* __restrict__ top_w,
    const int* __restrict__ offsets, int* __restrict__ cursors,
    int* __restrict__ row_token, float* __restrict__ row_weight)
{
    int t = blockIdx.x * blockDim.x + threadIdx.x;
    if (t >= T_TOK) return;
#pragma unroll
    for (int s = 0; s < 2; ++s) {
        int e = top_e[t * 2 + s];
        int pos = atomicAdd(&cursors[e], 1);
        int r = offsets[e] + pos;
        row_token[r] = t;
        row_weight[r] = top_w[t * 2 + s];
    }
}

// ---------------- FFN1: h = silu(x@w1^T) * (x@w3^T), grouped by expert ----------------
__global__ __launch_bounds__(256) void ffn1_kernel(
    const float* __restrict__ x, const float* __restrict__ w1, const float* __restrict__ w3,
    const int* __restrict__ counts, const int* __restrict__ offsets,
    const int* __restrict__ row_token, unsigned short* __restrict__ hbuf)
{
    int e = blockIdx.z;
    int cnt = counts[e];
    int m0 = blockIdx.y * 64;
    if (m0 >= cnt) return;
    int base = offsets[e];
    int n0 = blockIdx.x * 64;

    __shared__ unsigned short As[64 * LDST];
    __shared__ unsigned short B1s[64 * LDST];
    __shared__ unsigned short B3s[64 * LDST];

    int t = threadIdx.x;
    int lane = t & 63;
    int wid = t >> 6;
    int wm = wid >> 1, wn = wid & 1;
    int lr = lane & 15, lq = lane >> 4;

    int sr = t >> 2;           // staged row 0..63
    int sc = (t & 3) * 8;      // k offset 0,8,16,24

    int arow_valid = (m0 + sr) < cnt;
    int tokenRow = arow_valid ? row_token[base + m0 + sr] : 0;
    const float* aP  = x  + (size_t)tokenRow * H_DIM + sc;
    const float* b1P = w1 + ((size_t)e * F_DIM + (n0 + sr)) * H_DIM + sc;
    const float* b3P = w3 + ((size_t)e * F_DIM + (n0 + sr)) * H_DIM + sc;

    f32x4 acc1[2][2] = {{{0.f,0.f,0.f,0.f},{0.f,0.f,0.f,0.f}},{{0.f,0.f,0.f,0.f},{0.f,0.f,0.f,0.f}}};
    f32x4 acc3[2][2] = {{{0.f,0.f,0.f,0.f},{0.f,0.f,0.f,0.f}},{{0.f,0.f,0.f,0.f},{0.f,0.f,0.f,0.f}}};

    for (int k0 = 0; k0 < H_DIM; k0 += 32) {
        float4 a0, a1;
        if (arow_valid) { a0 = *(const float4*)(aP + k0); a1 = *(const float4*)(aP + k0 + 4); }
        else            { a0 = make_float4(0, 0, 0, 0);   a1 = a0; }
        float4 p0 = *(const float4*)(b1P + k0); float4 p1 = *(const float4*)(b1P + k0 + 4);
        float4 q0 = *(const float4*)(b3P + k0); float4 q1 = *(const float4*)(b3P + k0 + 4);
        unsigned short* d = As + sr * LDST + sc;
        d[0]=f2bf(a0.x); d[1]=f2bf(a0.y); d[2]=f2bf(a0.z); d[3]=f2bf(a0.w);
        d[4]=f2bf(a1.x); d[5]=f2bf(a1.y); d[6]=f2bf(a1.z); d[7]=f2bf(a1.w);
        d = B1s + sr * LDST + sc;
        d[0]=f2bf(p0.x); d[1]=f2bf(p0.y); d[2]=f2bf(p0.z); d[3]=f2bf(p0.w);
        d[4]=f2bf(p1.x); d[5]=f2bf(p1.y); d[6]=f2bf(p1.z); d[7]=f2bf(p1.w);
        d = B3s + sr * LDST + sc;
        d[0]=f2bf(q0.x); d[1]=f2bf(q0.y); d[2]=f2bf(q0.z); d[3]=f2bf(q0.w);
        d[4]=f2bf(q1.x); d[5]=f2bf(q1.y); d[6]=f2bf(q1.z); d[7]=f2bf(q1.w);
        __syncthreads();

        bf16x8 af[2], b1f[2], b3f[2];
#pragma unroll
        for (int ms = 0; ms < 2; ++ms)
            af[ms] = *(bf16x8*)(As + (wm * 32 + ms * 16 + lr) * LDST + lq * 8);
#pragma unroll
        for (int ns = 0; ns < 2; ++ns) {
            b1f[ns] = *(bf16x8*)(B1s + (wn * 32 + ns * 16 + lr) * LDST + lq * 8);
            b3f[ns] = *(bf16x8*)(B3s + (wn * 32 + ns * 16 + lr) * LDST + lq * 8);
        }
#pragma unroll
        for (int ms = 0; ms < 2; ++ms)
#pragma unroll
            for (int ns = 0; ns < 2; ++ns) {
                acc1[ms][ns] = __builtin_amdgcn_mfma_f32_16x16x32_bf16(af[ms], b1f[ns], acc1[ms][ns], 0, 0, 0);
                acc3[ms][ns] = __builtin_amdgcn_mfma_f32_16x16x32_bf16(af[ms], b3f[ns], acc3[ms][ns], 0, 0, 0);
            }
        __syncthreads();
    }

#pragma unroll
    for (int ms = 0; ms < 2; ++ms) {
        int r0 = wm * 32 + ms * 16 + lq * 4;
#pragma unroll
        for (int ns = 0; ns < 2; ++ns) {
            int c = n0 + wn * 32 + ns * 16 + lr;
#pragma unroll
            for (int i = 0; i < 4; ++i) {
                int r = r0 + i;
                if (m0 + r < cnt) {
                    float a = acc1[ms][ns][i];
                    float hv = (a / (1.f + __expf(-a))) * acc3[ms][ns][i];
                    hbuf[(size_t)(base + m0 + r) * F_DIM + c] = f2bf(hv);
                }
            }
        }
    }
}

// ---------------- FFN2: out[token] += weight * (h @ w2^T) ----------------
__global__ __launch_bounds__(256) void ffn2_kernel(
    const unsigned short* __restrict__ hbuf, const float* __restrict__ w2,
    const int* __restrict__ counts, const int* __restrict__ offsets,
    const int* __restrict__ row_token, const float* __restrict__ row_weight,
    float* __restrict__ out)
{
    int e = blockIdx.z;
    int cnt = counts[e];
    int m0 = blockIdx.y * 64;
    if (m0 >= cnt) return;
    int base = offsets[e];
    int n0 = blockIdx.x * 64;

    __shared__ unsigned short As[64 * LDST];
    __shared__ unsigned short Bs[64 * LDST];

    int t = threadIdx.x;
    int lane = t & 63;
    int wid = t >> 6;
    int wm = wid >> 1, wn = wid & 1;
    int lr = lane & 15, lq = lane >> 4;

    int sr = t >> 2;
    int sc = (t & 3) * 8;

    int arow_valid = (m0 + sr) < cnt;
    const unsigned short* aP = hbuf + (size_t)(base + m0 + (arow_valid ? sr : 0)) * F_DIM + sc;
    const float* bP = w2 + ((size_t)e * H_DIM + (n0 + sr)) * F_DIM + sc;

    f32x4 acc[2][2] = {{{0.f,0.f,0.f,0.f},{0.f,0.f,0.f,0.f}},{{0.f,0.f,0.f,0.f},{0.f,0.f,0.f,0.f}}};

    for (int k0 = 0; k0 < F_DIM; k0 += 32) {
        uint4 av = make_uint4(0, 0, 0, 0);
        if (arow_valid) av = *(const uint4*)(aP + k0);
        float4 p0 = *(const float4*)(bP + k0); float4 p1 = *(const float4*)(bP + k0 + 4);
        *(uint4*)(As + sr * LDST + sc) = av;
        unsigned short* d = Bs + sr * LDST + sc;
        d[0]=f2bf(p0.x); d[1]=f2bf(p0.y); d[2]=f2bf(p0.z); d[3]=f2bf(p0.w);
        d[4]=f2bf(p1.x); d[5]=f2bf(p1.y); d[6]=f2bf(p1.z); d[7]=f2bf(p1.w);
        __syncthreads();

        bf16x8 af[2], bf[2];
#pragma unroll
        for (int ms = 0; ms < 2; ++ms)
            af[ms] = *(bf16x8*)(As + (wm * 32 + ms * 16 + lr) * LDST + lq * 8);
#pragma unroll
        for (int ns = 0; ns < 2; ++ns)
            bf[ns] = *(bf16x8*)(Bs + (wn * 32 + ns * 16 + lr) * LDST + lq * 8);
#pragma unroll
        for (int ms = 0; ms < 2; ++ms)
#pragma unroll
            for (int ns = 0; ns < 2; ++ns)
                acc[ms][ns] = __builtin_amdgcn_mfma_f32_16x16x32_bf16(af[ms], bf[ns], acc[ms][ns], 0, 0, 0);
        __syncthreads();
    }

#pragma unroll
    for (int ms = 0; ms < 2; ++ms) {
        int r0 = wm * 32 + ms * 16 + lq * 4;
#pragma unroll
        for (int i = 0; i < 4; ++i) {
            int r = r0 + i;
            if (m0 + r < cnt) {
                int token = row_token[base + m0 + r];
                float wgt = row_weight[base + m0 + r];
#pragma unroll
                for (int ns = 0; ns < 2; ++ns) {
                    int c = n0 + wn * 32 + ns * 16 + lr;
                    atomicAdd(&out[(size_t)token * H_DIM + c], acc[ms][ns][i] * wgt);
                }
            }
        }
    }
}

extern "C" void kernel_launch(void* const* d_in, const int* in_sizes, int n_in,
                              void* d_out, int out_size, void* d_ws, size_t ws_size,
                              hipStream_t stream)
{
    const float* x  = (const float*)d_in[0];
    const float* gw = (const float*)d_in[1];
    const float* w1 = (const float*)d_in[2];
    const float* w2 = (const float*)d_in[3];
    const float* w3 = (const float*)d_in[4];
    float* out = (float*)d_out;

    int* wsI = (int*)d_ws;
    int* counts  = wsI;             // 12 (rounded region)
    int* cursors = wsI + 16;        // 12
    int* offsets = wsI + 32;        // 13
    int* top_e   = wsI + 64;        // 2*T
    int* row_token = top_e + 2 * T_TOK;              // 2*T
    float* top_w     = (float*)(row_token + 2 * T_TOK);  // 2*T
    float* row_weight = top_w + 2 * T_TOK;               // 2*T
    unsigned short* hbuf = (unsigned short*)(row_weight + 2 * T_TOK);  // 2*T * F bf16

    hipMemsetAsync(counts, 0, 64 * sizeof(int), stream);
    hipMemsetAsync(out, 0, (size_t)out_size * sizeof(float), stream);

    gate_kernel<<<T_TOK / 4, 256, 0, stream>>>(x, gw, counts, top_e, top_w);
    scan_kernel<<<1, 64, 0, stream>>>(counts, offsets, cursors);
    scatter_kernel<<<T_TOK / 256, 256, 0, stream>>>(top_e, top_w, offsets, cursors,
                                                    row_token, row_weight);
    dim3 g1(F_DIM / 64, 64, NE);
    ffn1_kernel<<<g1, 256, 0, stream>>>(x, w1, w3, counts, offsets, row_token, hbuf);
    dim3 g2(H_DIM / 64, 64, NE);
    ffn2_kernel<<<g2, 256, 0, stream>>>(hbuf, w2, counts, offsets, row_token, row_weight, out);
}

// Round 2
// 839.765 us; speedup vs baseline: 1.0959x; 1.0959x over previous
//
#include <hip/hip_runtime.h>

#define T_TOK 4096
#define H_DIM 2048
#define F_DIM 1280
#define NE 12
#define TOTAL_ROWS (2 * T_TOK)

typedef float f32x4 __attribute__((ext_vector_type(4)));
typedef short bf16x8 __attribute__((ext_vector_type(8)));

__device__ __forceinline__ unsigned short f2bf(float f) {
    unsigned int u = __float_as_uint(f);
    u += 0x7FFFu + ((u >> 16) & 1u);   // RNE
    return (unsigned short)(u >> 16);
}

// async global->LDS, 16B per lane. LDS dest = wave-uniform base + lane*16.
__device__ __forceinline__ void gl2lds16(const void* g, void* l) {
    __builtin_amdgcn_global_load_lds(
        (const __attribute__((address_space(1))) unsigned int*)g,
        (__attribute__((address_space(3))) unsigned int*)l,
        16, 0, 0);
}

// ---------------- fp32 -> bf16 streaming convert (8 elems/thread) ----------------
__global__ __launch_bounds__(256) void convert_kernel(
    const float* __restrict__ src, unsigned short* __restrict__ dst)
{
    size_t i = ((size_t)blockIdx.x * 256 + threadIdx.x) * 8;
    float4 a = *(const float4*)(src + i);
    float4 b = *(const float4*)(src + i + 4);
    unsigned short o[8];
    o[0] = f2bf(a.x); o[1] = f2bf(a.y); o[2] = f2bf(a.z); o[3] = f2bf(a.w);
    o[4] = f2bf(b.x); o[5] = f2bf(b.y); o[6] = f2bf(b.z); o[7] = f2bf(b.w);
    *(uint4*)(dst + i) = *(const uint4*)o;
}

// ---------------- gating: fp32 logits, top-2, normalized weights ----------------
__global__ __launch_bounds__(256) void gate_kernel(
    const float* __restrict__ x, const float* __restrict__ gw,
    int* __restrict__ counts, int* __restrict__ top_e, float* __restrict__ top_w)
{
    int gid = blockIdx.x * blockDim.x + threadIdx.x;
    int tok = gid >> 6;
    int lane = threadIdx.x & 63;
    if (tok >= T_TOK) return;
    const float* xr = x + (size_t)tok * H_DIM;
    float4 xs[8];
#pragma unroll
    for (int c = 0; c < 8; ++c) xs[c] = *(const float4*)(xr + c * 256 + lane * 4);
    float acc[NE];
#pragma unroll
    for (int e = 0; e < NE; ++e) {
        const float* gr = gw + (size_t)e * H_DIM;
        float s = 0.f;
#pragma unroll
        for (int c = 0; c < 8; ++c) {
            float4 g = *(const float4*)(gr + c * 256 + lane * 4);
            s += xs[c].x * g.x + xs[c].y * g.y + xs[c].z * g.z + xs[c].w * g.w;
        }
        acc[e] = s;
    }
#pragma unroll
    for (int e = 0; e < NE; ++e) {
#pragma unroll
        for (int off = 32; off > 0; off >>= 1)
            acc[e] += __shfl_xor(acc[e], off, 64);
    }
    if (lane == 0) {
        int b0 = 0;
#pragma unroll
        for (int e = 1; e < NE; ++e) if (acc[e] > acc[b0]) b0 = e;
        int b1 = (b0 == 0) ? 1 : 0;
#pragma unroll
        for (int e = 0; e < NE; ++e) if (e != b0 && acc[e] > acc[b1]) b1 = e;
        float t = __expf(acc[b1] - acc[b0]);   // <= 1
        float w0 = 1.f / (1.f + t);
        top_e[tok * 2] = b0; top_e[tok * 2 + 1] = b1;
        top_w[tok * 2] = w0; top_w[tok * 2 + 1] = 1.f - w0;
        atomicAdd(&counts[b0], 1);
        atomicAdd(&counts[b1], 1);
    }
}

__global__ void scan_kernel(const int* __restrict__ counts, int* __restrict__ offsets,
                            int* __restrict__ cursors)
{
    if (threadIdx.x == 0 && blockIdx.x == 0) {
        int s = 0;
        for (int e = 0; e < NE; ++e) { offsets[e] = s; s += counts[e]; cursors[e] = 0; }
        offsets[NE] = s;
    }
}

__global__ __launch_bounds__(256) void scatter_kernel(
    const int* __restrict__ top_e, const float* __restrict__ top_w,
    const int* __restrict__ offsets, int* __restrict__ cursors,
    int* __restrict__ row_token, float* __restrict__ row_weight,
    int* __restrict__ inv_pos)
{
    int t = blockIdx.x * blockDim.x + threadIdx.x;
    if (t >= T_TOK) return;
#pragma unroll
    for (int s = 0; s < 2; ++s) {
        int e = top_e[t * 2 + s];
        int pos = atomicAdd(&cursors[e], 1);
        int r = offsets[e] + pos;
        row_token[r] = t;
        row_weight[r] = top_w[t * 2 + s];
        inv_pos[t * 2 + s] = r;
    }
}

// ---------------- FFN1: h = silu(x@w1^T) * (x@w3^T); 128x128x32 tiles ----------------
__global__ __launch_bounds__(256) void ffn1_kernel(
    const unsigned short* __restrict__ xb, const unsigned short* __restrict__ w1b,
    const unsigned short* __restrict__ w3b,
    const int* __restrict__ counts, const int* __restrict__ offsets,
    const int* __restrict__ row_token, unsigned short* __restrict__ hbuf)
{
    int e = blockIdx.z;
    int cnt = counts[e];
    int m0 = blockIdx.y * 128;
    if (m0 >= cnt) return;
    int base = offsets[e];
    int n0 = blockIdx.x * 128;

    __shared__ unsigned short As[128 * 32];
    __shared__ unsigned short B1s[128 * 32];
    __shared__ unsigned short B3s[128 * 32];

    int t = threadIdx.x;
    int lane = t & 63;
    int wid = t >> 6;
    int wm = wid >> 1, wn = wid & 1;
    int lr = lane & 15, lq = lane >> 4;

    // staging: issue j covers rows j*64 + (t>>2), 16B chunk (t&3)
    int srow = t >> 2;
    int chunk = t & 3;
    int tok0 = row_token[base + min(m0 + srow, cnt - 1)];
    int tok1 = row_token[base + min(m0 + 64 + srow, cnt - 1)];
    const unsigned short* gA0 = xb + (size_t)tok0 * H_DIM + chunk * 8;
    const unsigned short* gA1 = xb + (size_t)tok1 * H_DIM + chunk * 8;
    const unsigned short* gB1 = w1b + ((size_t)e * F_DIM + n0 + srow) * H_DIM + chunk * 8;
    const unsigned short* gB3 = w3b + ((size_t)e * F_DIM + n0 + srow) * H_DIM + chunk * 8;
    const size_t rowskip = (size_t)64 * H_DIM;

    // wave-uniform LDS bases (thread t lands at byte t*16 within each half-tile)
    unsigned short* lA0 = As + wid * 512;
    unsigned short* lA1 = As + 2048 + wid * 512;
    unsigned short* lB10 = B1s + wid * 512;
    unsigned short* lB11 = B1s + 2048 + wid * 512;
    unsigned short* lB30 = B3s + wid * 512;
    unsigned short* lB31 = B3s + 2048 + wid * 512;

    f32x4 acc1[4][4] = {};
    f32x4 acc3[4][4] = {};

    for (int k0 = 0; k0 < H_DIM; k0 += 32) {
        gl2lds16(gA0 + k0, lA0);
        gl2lds16(gA1 + k0, lA1);
        gl2lds16(gB1 + k0, lB10);
        gl2lds16(gB1 + rowskip + k0, lB11);
        gl2lds16(gB3 + k0, lB30);
        gl2lds16(gB3 + rowskip + k0, lB31);
        __syncthreads();

        bf16x8 af[4];
#pragma unroll
        for (int ms = 0; ms < 4; ++ms)
            af[ms] = *(const bf16x8*)(As + (wm * 64 + ms * 16 + lr) * 32 + lq * 8);
#pragma unroll
        for (int ns = 0; ns < 4; ++ns) {
            bf16x8 b1 = *(const bf16x8*)(B1s + (wn * 64 + ns * 16 + lr) * 32 + lq * 8);
            bf16x8 b3 = *(const bf16x8*)(B3s + (wn * 64 + ns * 16 + lr) * 32 + lq * 8);
#pragma unroll
            for (int ms = 0; ms < 4; ++ms) {
                acc1[ms][ns] = __builtin_amdgcn_mfma_f32_16x16x32_bf16(af[ms], b1, acc1[ms][ns], 0, 0, 0);
                acc3[ms][ns] = __builtin_amdgcn_mfma_f32_16x16x32_bf16(af[ms], b3, acc3[ms][ns], 0, 0, 0);
            }
        }
        __syncthreads();
    }

#pragma unroll
    for (int ms = 0; ms < 4; ++ms) {
#pragma unroll
        for (int i = 0; i < 4; ++i) {
            int r = wm * 64 + ms * 16 + lq * 4 + i;
            if (m0 + r < cnt) {
                size_t rowoff = (size_t)(base + m0 + r) * F_DIM;
#pragma unroll
                for (int ns = 0; ns < 4; ++ns) {
                    int c = n0 + wn * 64 + ns * 16 + lr;
                    float a = acc1[ms][ns][i];
                    float hv = (a / (1.f + __expf(-a))) * acc3[ms][ns][i];
                    hbuf[rowoff + c] = f2bf(hv);
                }
            }
        }
    }
}

// ---------------- FFN2: ybuf[row] = weight * (h @ w2^T); 128x128x32 tiles ----------------
__global__ __launch_bounds__(256) void ffn2_kernel(
    const unsigned short* __restrict__ hbuf, const unsigned short* __restrict__ w2b,
    const int* __restrict__ counts, const int* __restrict__ offsets,
    const float* __restrict__ row_weight, float* __restrict__ ybuf)
{
    int e = blockIdx.z;
    int cnt = counts[e];
    int m0 = blockIdx.y * 128;
    if (m0 >= cnt) return;
    int base = offsets[e];
    int n0 = blockIdx.x * 128;

    __shared__ unsigned short As[128 * 32];
    __shared__ unsigned short Bs[128 * 32];

    int t = threadIdx.x;
    int lane = t & 63;
    int wid = t >> 6;
    int wm = wid >> 1, wn = wid & 1;
    int lr = lane & 15, lq = lane >> 4;

    int srow = t >> 2;
    int chunk = t & 3;
    const unsigned short* gA0 = hbuf + (size_t)(base + min(m0 + srow, cnt - 1)) * F_DIM + chunk * 8;
    const unsigned short* gA1 = hbuf + (size_t)(base + min(m0 + 64 + srow, cnt - 1)) * F_DIM + chunk * 8;
    const unsigned short* gB = w2b + ((size_t)e * H_DIM + n0 + srow) * F_DIM + chunk * 8;
    const size_t rowskip = (size_t)64 * F_DIM;

    unsigned short* lA0 = As + wid * 512;
    unsigned short* lA1 = As + 2048 + wid * 512;
    unsigned short* lB0 = Bs + wid * 512;
    unsigned short* lB1 = Bs + 2048 + wid * 512;

    f32x4 acc[4][4] = {};

    for (int k0 = 0; k0 < F_DIM; k0 += 32) {
        gl2lds16(gA0 + k0, lA0);
        gl2lds16(gA1 + k0, lA1);
        gl2lds16(gB + k0, lB0);
        gl2lds16(gB + rowskip + k0, lB1);
        __syncthreads();

        bf16x8 af[4];
#pragma unroll
        for (int ms = 0; ms < 4; ++ms)
            af[ms] = *(const bf16x8*)(As + (wm * 64 + ms * 16 + lr) * 32 + lq * 8);
#pragma unroll
        for (int ns = 0; ns < 4; ++ns) {
            bf16x8 b = *(const bf16x8*)(Bs + (wn * 64 + ns * 16 + lr) * 32 + lq * 8);
#pragma unroll
            for (int ms = 0; ms < 4; ++ms)
                acc[ms][ns] = __builtin_amdgcn_mfma_f32_16x16x32_bf16(af[ms], b, acc[ms][ns], 0, 0, 0);
        }
        __syncthreads();
    }

#pragma unroll
    for (int ms = 0; ms < 4; ++ms) {
#pragma unroll
        for (int i = 0; i < 4; ++i) {
            int r = wm * 64 + ms * 16 + lq * 4 + i;
            if (m0 + r < cnt) {
                float wgt = row_weight[base + m0 + r];
                size_t rowoff = (size_t)(base + m0 + r) * H_DIM;
#pragma unroll
                for (int ns = 0; ns < 4; ++ns) {
                    int c = n0 + wn * 64 + ns * 16 + lr;
                    ybuf[rowoff + c] = acc[ms][ns][i] * wgt;
                }
            }
        }
    }
}

// ---------------- combine: out[t] = ybuf[pos0] + ybuf[pos1] ----------------
__global__ __launch_bounds__(256) void combine_kernel(
    const float* __restrict__ ybuf, const int* __restrict__ inv_pos,
    float* __restrict__ out)
{
    int tk = blockIdx.x;
    int p0 = inv_pos[2 * tk];
    int p1 = inv_pos[2 * tk + 1];
    const float4* y0 = (const float4*)(ybuf + (size_t)p0 * H_DIM);
    const float4* y1 = (const float4*)(ybuf + (size_t)p1 * H_DIM);
    float4* o = (float4*)(out + (size_t)tk * H_DIM);
#pragma unroll
    for (int i = threadIdx.x; i < H_DIM / 4; i += 256) {
        float4 a = y0[i], b = y1[i];
        float4 r;
        r.x = a.x + b.x; r.y = a.y + b.y; r.z = a.z + b.z; r.w = a.w + b.w;
        o[i] = r;
    }
}

extern "C" void kernel_launch(void* const* d_in, const int* in_sizes, int n_in,
                              void* d_out, int out_size, void* d_ws, size_t ws_size,
                              hipStream_t stream)
{
    const float* x  = (const float*)d_in[0];
    const float* gw = (const float*)d_in[1];
    const float* w1 = (const float*)d_in[2];
    const float* w2 = (const float*)d_in[3];
    const float* w3 = (const float*)d_in[4];
    float* out = (float*)d_out;

    // ---- workspace carve-up ----
    unsigned char* p = (unsigned char*)d_ws;
    int* counts     = (int*)p;  p += 256;
    int* cursors    = (int*)p;  p += 256;
    int* offsets    = (int*)p;  p += 256;
    int* top_e      = (int*)p;  p += 2 * T_TOK * 4;
    float* top_w    = (float*)p; p += 2 * T_TOK * 4;
    int* row_token  = (int*)p;  p += 2 * T_TOK * 4;
    float* row_weight = (float*)p; p += 2 * T_TOK * 4;
    int* inv_pos    = (int*)p;  p += 2 * T_TOK * 4;
    unsigned short* xb  = (unsigned short*)p; p += (size_t)T_TOK * H_DIM * 2;
    unsigned short* w2b = (unsigned short*)p; p += (size_t)NE * H_DIM * F_DIM * 2;
    unsigned short* hb  = (unsigned short*)p; p += (size_t)TOTAL_ROWS * F_DIM * 2;
    // union: w1b+w3b (bf16, used through ffn1) overlaps ybuf (fp32, used after)
    unsigned short* w1b = (unsigned short*)p;
    unsigned short* w3b = (unsigned short*)(p + (size_t)NE * F_DIM * H_DIM * 2);
    float* ybuf = (float*)p;

    // ---- bf16 conversions (sizes divide 8*256 exactly) ----
    const int WELEM = NE * F_DIM * H_DIM;           // 31,457,280
    convert_kernel<<<T_TOK * H_DIM / 2048, 256, 0, stream>>>(x, xb);
    convert_kernel<<<WELEM / 2048, 256, 0, stream>>>(w1, w1b);
    convert_kernel<<<WELEM / 2048, 256, 0, stream>>>(w2, w2b);
    convert_kernel<<<WELEM / 2048, 256, 0, stream>>>(w3, w3b);

    hipMemsetAsync(counts, 0, 64 * sizeof(int), stream);
    gate_kernel<<<T_TOK / 4, 256, 0, stream>>>(x, gw, counts, top_e, top_w);
    scan_kernel<<<1, 64, 0, stream>>>(counts, offsets, cursors);
    scatter_kernel<<<T_TOK / 256, 256, 0, stream>>>(top_e, top_w, offsets, cursors,
                                                    row_token, row_weight, inv_pos);

    dim3 g1(F_DIM / 128, 32, NE);   // (10, 32, 12)
    ffn1_kernel<<<g1, 256, 0, stream>>>(xb, w1b, w3b, counts, offsets, row_token, hb);

    dim3 g2(H_DIM / 128, 32, NE);   // (16, 32, 12)
    ffn2_kernel<<<g2, 256, 0, stream>>>(hb, w2b, counts, offsets, row_weight, ybuf);

    combine_kernel<<<T_TOK, 256, 0, stream>>>(ybuf, inv_pos, out);
}